// Round 8
// baseline (50.562 us; speedup 1.0000x reference)
//
#include <hip/hip_runtime.h>

#define D 256
#define NBLOCKS 1024
#define WPB 4
#define EPS 1e-8f
#define NB2 64                    // stage-2 blocks
#define ROWS2 (NBLOCKS / NB2)     // 16 partial rows per stage-2 block

// ---------------- Stage 1: stream rows, per-block partial column sums ----------------
__global__ __launch_bounds__(256) void gc_partial(
    const float* __restrict__ feat,
    const int* __restrict__ known,
    const int* __restrict__ unknown,
    float* __restrict__ partials,   // [NBLOCKS][3*D]
    float* __restrict__ acc,        // [3*D] zeroed here for stage 2
    unsigned int* __restrict__ ticket,
    int N)
{
    // block 0 resets stage-2 scratch; visible to stage 2 via end-of-kernel release
    if (blockIdx.x == 0) {
        acc[threadIdx.x] = 0.f;
        acc[D + threadIdx.x] = 0.f;
        acc[2 * D + threadIdx.x] = 0.f;
        if (threadIdx.x == 0) *ticket = 0u;
    }

    const int lane = threadIdx.x & 63;
    const int wave = threadIdx.x >> 6;
    const int gw   = blockIdx.x * WPB + wave;
    const int nw   = gridDim.x * WPB;

    float4 aAll = {0.f, 0.f, 0.f, 0.f};
    float4 aK   = {0.f, 0.f, 0.f, 0.f};
    float4 aU   = {0.f, 0.f, 0.f, 0.f};

    // 2 rows per wave-iteration: 2 independent 1KB loads in flight,
    // 2 interleaved shuffle-reduce chains. (round-6 known-good body)
    for (int r = gw * 2; r < N; r += nw * 2) {
        const int r1 = r + 1;
        const bool has2 = (r1 < N);                // wave-uniform
        const float4* rp = (const float4*)(feat + (size_t)r * D);
        float4 v0 = rp[lane];
        float4 v1 = {0.f, 0.f, 0.f, 0.f};
        int kn0 = known[r],  un0 = unknown[r];
        int kn1 = 0, un1 = 0;
        if (has2) {
            v1  = rp[64 + lane];
            kn1 = known[r1];
            un1 = unknown[r1];
        }

        float s0 = v0.x*v0.x + v0.y*v0.y + v0.z*v0.z + v0.w*v0.w;
        float s1 = v1.x*v1.x + v1.y*v1.y + v1.z*v1.z + v1.w*v1.w;
        #pragma unroll
        for (int off = 32; off > 0; off >>= 1) {   // interleaved chains
            s0 += __shfl_xor(s0, off);
            s1 += __shfl_xor(s1, off);
        }
        float i0 = 1.0f / fmaxf(sqrtf(s0), EPS);
        float i1 = 1.0f / fmaxf(sqrtf(s1), EPS);

        float ux0 = v0.x*i0, uy0 = v0.y*i0, uz0 = v0.z*i0, uw0 = v0.w*i0;
        float ux1 = v1.x*i1, uy1 = v1.y*i1, uz1 = v1.z*i1, uw1 = v1.w*i1;

        aAll.x += ux0 + ux1; aAll.y += uy0 + uy1;
        aAll.z += uz0 + uz1; aAll.w += uw0 + uw1;
        if (kn0) { aK.x += ux0; aK.y += uy0; aK.z += uz0; aK.w += uw0; }
        if (kn1) { aK.x += ux1; aK.y += uy1; aK.z += uz1; aK.w += uw1; }
        if (un0) { aU.x += ux0; aU.y += uy0; aU.z += uz0; aU.w += uw0; }
        if (un1) { aU.x += ux1; aU.y += uy1; aU.z += uz1; aU.w += uw1; }
    }

    // block reduce: wave writes its 256-col partial; 256 threads sum columns
    __shared__ float red[WPB][D];
    float* pout = partials + (size_t)blockIdx.x * (3 * D);
    float4 accs[3] = {aAll, aK, aU};
    #pragma unroll
    for (int a = 0; a < 3; ++a) {
        float4 t = accs[a];
        red[wave][lane * 4 + 0] = t.x;
        red[wave][lane * 4 + 1] = t.y;
        red[wave][lane * 4 + 2] = t.z;
        red[wave][lane * 4 + 3] = t.w;
        __syncthreads();
        const int col = threadIdx.x;
        float s = red[0][col] + red[1][col] + red[2][col] + red[3][col];
        pout[a * D + col] = s;                     // plain coalesced store
        __syncthreads();
    }
}

// ---------------- Stage 2: 64 blocks reduce + last block finalizes ----------------
__global__ __launch_bounds__(768) void gc_reduce_final(
    const float* __restrict__ partials,   // [NBLOCKS][768] (inter-kernel: plain loads ok)
    float* __restrict__ acc,              // [768], zeroed by stage 1
    unsigned int* __restrict__ ticket,    // zeroed by stage 1
    float* __restrict__ out, int N)
{
    const int t = threadIdx.x;            // 0..767, coalesced across columns
    const float* base = partials + (size_t)blockIdx.x * ROWS2 * (3 * D) + t;
    float s = 0.f;
    #pragma unroll
    for (int i = 0; i < ROWS2; ++i)
        s += base[(size_t)i * (3 * D)];
    atomicAdd(acc + t, s);                // 64*768 = 49K device atomics total

    __threadfence();                      // cheap at 64 blocks; orders before ticket
    __syncthreads();
    __shared__ int is_last;
    if (t == 0)
        is_last = (atomicAdd(ticket, 1u) == (unsigned int)(NB2 - 1));
    __syncthreads();
    if (!is_last) return;

    // last block: coherent-point reads (plain loads could hit stale XCD L2)
    float v = atomicAdd(acc + t, 0.0f);
    __shared__ float ls[3 * D];
    ls[t] = v;
    __syncthreads();

    if (t < D) {
        const float sa = ls[t];
        const float sk = ls[D + t];
        const float su = ls[2 * D + t];
        float p1 = sa * sk;
        float p2 = sk * sk;
        float p3 = sk * su;
        #pragma unroll
        for (int off = 32; off > 0; off >>= 1) {
            p1 += __shfl_xor(p1, off);
            p2 += __shfl_xor(p2, off);
            p3 += __shfl_xor(p3, off);
        }
        __shared__ float r[3][4];
        const int wave = t >> 6, lane = t & 63;
        if (lane == 0) { r[0][wave] = p1; r[1][wave] = p2; r[2][wave] = p3; }
        __syncthreads();
        if (t == 0) {
            float t1 = r[0][0] + r[0][1] + r[0][2] + r[0][3];
            float t2 = r[1][0] + r[1][1] + r[1][2] + r[1][3];
            float t3 = r[2][0] + r[2][1] + r[2][2] + r[2][3];
            float gain = t1 - 0.5f * t2 - t3;      // LAMDA=0.5, ETA=1.0
            out[0] = -gain / (float)N;
        }
    }
}

extern "C" void kernel_launch(void* const* d_in, const int* in_sizes, int n_in,
                              void* d_out, int out_size, void* d_ws, size_t ws_size,
                              hipStream_t stream) {
    const float* feat    = (const float*)d_in[0];
    const int*   known   = (const int*)d_in[1];
    const int*   unknown = (const int*)d_in[2];
    const int N = in_sizes[1];

    // ws layout: acc[768] | ticket | pad | partials[NBLOCKS][768]
    float* acc = (float*)d_ws;
    unsigned int* ticket = (unsigned int*)((char*)d_ws + 3 * D * sizeof(float));
    float* partials = (float*)((char*)d_ws + 3 * D * sizeof(float) + 256);

    gc_partial<<<NBLOCKS, 256, 0, stream>>>(feat, known, unknown, partials,
                                            acc, ticket, N);
    gc_reduce_final<<<NB2, 768, 0, stream>>>(partials, acc, ticket,
                                             (float*)d_out, N);
}

// Round 9
// 42.200 us; speedup vs baseline: 1.1981x; 1.1981x over previous
//
#include <hip/hip_runtime.h>

#define D 256
#define NBLOCKS 1024
#define WPB 4
#define EPS 1e-8f
#define NB2 32                    // stage-2a blocks
#define ROWS2 (NBLOCKS / NB2)     // 32 partial rows per stage-2a block
#define ROWF4 192                 // 768 floats = 192 float4 per partial row

// ---------------- Stage 1: stream rows, per-block partial column sums ----------------
// (verbatim round-6 known-good: 42.5 us total config)
__global__ __launch_bounds__(256) void gc_partial(
    const float* __restrict__ feat,
    const int* __restrict__ known,
    const int* __restrict__ unknown,
    float* __restrict__ partials,   // [NBLOCKS][3*D]
    int N)
{
    const int lane = threadIdx.x & 63;
    const int wave = threadIdx.x >> 6;
    const int gw   = blockIdx.x * WPB + wave;
    const int nw   = gridDim.x * WPB;

    float4 aAll = {0.f, 0.f, 0.f, 0.f};
    float4 aK   = {0.f, 0.f, 0.f, 0.f};
    float4 aU   = {0.f, 0.f, 0.f, 0.f};

    for (int r = gw * 2; r < N; r += nw * 2) {
        const int r1 = r + 1;
        const bool has2 = (r1 < N);                // wave-uniform
        const float4* rp = (const float4*)(feat + (size_t)r * D);
        float4 v0 = rp[lane];
        float4 v1 = {0.f, 0.f, 0.f, 0.f};
        int kn0 = known[r],  un0 = unknown[r];
        int kn1 = 0, un1 = 0;
        if (has2) {
            v1  = rp[64 + lane];
            kn1 = known[r1];
            un1 = unknown[r1];
        }

        float s0 = v0.x*v0.x + v0.y*v0.y + v0.z*v0.z + v0.w*v0.w;
        float s1 = v1.x*v1.x + v1.y*v1.y + v1.z*v1.z + v1.w*v1.w;
        #pragma unroll
        for (int off = 32; off > 0; off >>= 1) {   // interleaved chains
            s0 += __shfl_xor(s0, off);
            s1 += __shfl_xor(s1, off);
        }
        float i0 = 1.0f / fmaxf(sqrtf(s0), EPS);
        float i1 = 1.0f / fmaxf(sqrtf(s1), EPS);

        float ux0 = v0.x*i0, uy0 = v0.y*i0, uz0 = v0.z*i0, uw0 = v0.w*i0;
        float ux1 = v1.x*i1, uy1 = v1.y*i1, uz1 = v1.z*i1, uw1 = v1.w*i1;

        aAll.x += ux0 + ux1; aAll.y += uy0 + uy1;
        aAll.z += uz0 + uz1; aAll.w += uw0 + uw1;
        if (kn0) { aK.x += ux0; aK.y += uy0; aK.z += uz0; aK.w += uw0; }
        if (kn1) { aK.x += ux1; aK.y += uy1; aK.z += uz1; aK.w += uw1; }
        if (un0) { aU.x += ux0; aU.y += uy0; aU.z += uz0; aU.w += uw0; }
        if (un1) { aU.x += ux1; aU.y += uy1; aU.z += uz1; aU.w += uw1; }
    }

    __shared__ float red[WPB][D];
    float* pout = partials + (size_t)blockIdx.x * (3 * D);
    float4 accs[3] = {aAll, aK, aU};
    #pragma unroll
    for (int a = 0; a < 3; ++a) {
        float4 t = accs[a];
        red[wave][lane * 4 + 0] = t.x;
        red[wave][lane * 4 + 1] = t.y;
        red[wave][lane * 4 + 2] = t.z;
        red[wave][lane * 4 + 3] = t.w;
        __syncthreads();
        const int col = threadIdx.x;
        float s = red[0][col] + red[1][col] + red[2][col] + red[3][col];
        pout[a * D + col] = s;
        __syncthreads();
    }
}

// ---------------- Stage 2a: 32 blocks, float4 loads, 32 rows each ----------------
__global__ __launch_bounds__(ROWF4) void gc_reduce1(
    const float4* __restrict__ partials,   // [NBLOCKS][192] float4
    float4* __restrict__ partials2)        // [NB2][192] float4
{
    const int t = threadIdx.x;             // 0..191, coalesced 16B/lane
    const float4* base = partials + (size_t)blockIdx.x * ROWS2 * ROWF4 + t;
    float4 s = {0.f, 0.f, 0.f, 0.f};
    #pragma unroll 8
    for (int i = 0; i < ROWS2; ++i) {
        float4 v = base[(size_t)i * ROWF4];
        s.x += v.x; s.y += v.y; s.z += v.z; s.w += v.w;
    }
    partials2[(size_t)blockIdx.x * ROWF4 + t] = s;
}

// ---------------- Stage 2b: 1 block, float4 loads, finalize ----------------
__global__ __launch_bounds__(ROWF4) void gc_final(
    const float4* __restrict__ partials2, float* __restrict__ out, int N)
{
    const int t = threadIdx.x;             // 0..191
    float4 s = {0.f, 0.f, 0.f, 0.f};
    #pragma unroll
    for (int i = 0; i < NB2; ++i) {
        float4 v = partials2[(size_t)i * ROWF4 + t];
        s.x += v.x; s.y += v.y; s.z += v.z; s.w += v.w;
    }
    __shared__ float4 ls[ROWF4];
    ls[t] = s;
    __syncthreads();

    if (t < 64) {                          // one wave does the three dots
        float4 sa = ls[t];                 // s_all     cols 4t..4t+3
        float4 sk = ls[64 + t];            // s_known
        float4 su = ls[128 + t];           // s_unknown
        float p1 = sa.x*sk.x + sa.y*sk.y + sa.z*sk.z + sa.w*sk.w;
        float p2 = sk.x*sk.x + sk.y*sk.y + sk.z*sk.z + sk.w*sk.w;
        float p3 = sk.x*su.x + sk.y*su.y + sk.z*su.z + sk.w*su.w;
        #pragma unroll
        for (int off = 32; off > 0; off >>= 1) {
            p1 += __shfl_xor(p1, off);
            p2 += __shfl_xor(p2, off);
            p3 += __shfl_xor(p3, off);
        }
        if (t == 0) {
            float gain = p1 - 0.5f * p2 - p3;   // LAMDA=0.5, ETA=1.0
            out[0] = -gain / (float)N;
        }
    }
}

extern "C" void kernel_launch(void* const* d_in, const int* in_sizes, int n_in,
                              void* d_out, int out_size, void* d_ws, size_t ws_size,
                              hipStream_t stream) {
    const float* feat    = (const float*)d_in[0];
    const int*   known   = (const int*)d_in[1];
    const int*   unknown = (const int*)d_in[2];
    const int N = in_sizes[1];

    float* partials  = (float*)d_ws;   // 1024*768 floats = 3 MB
    float4* partials2 = (float4*)((char*)d_ws + (size_t)NBLOCKS * 3 * D * sizeof(float));

    gc_partial<<<NBLOCKS, 256, 0, stream>>>(feat, known, unknown, partials, N);
    gc_reduce1<<<NB2, ROWF4, 0, stream>>>((const float4*)partials, partials2);
    gc_final<<<1, ROWF4, 0, stream>>>((const float4*)partials2, (float*)d_out, N);
}